// Round 9
// baseline (383.229 us; speedup 1.0000x reference)
//
#include <hip/hip_runtime.h>

#define N_NODES 10000
#define N_EDGES 320000
#define N_PAIRS 1000000
#define NBUCK 8
#define NBUCK2 64
#define BUCKW 1250   // N_NODES / 8
#define BCAP 17408   // per-bucket capacity (expected 15625, sigma~124)

typedef unsigned short ushort_t;
typedef __attribute__((ext_vector_type(8))) short short8;
typedef __attribute__((ext_vector_type(4))) float floatx4;
typedef _Float16 half2_t __attribute__((ext_vector_type(2)));

__device__ inline float blo(unsigned int u) { return __uint_as_float(u << 16); }
__device__ inline float bhi(unsigned int u) { return __uint_as_float(u & 0xffff0000u); }
__device__ inline ushort_t f2bf(float f) {
    unsigned int u = __float_as_uint(f);
    unsigned int r = (u + 0x7fffu + ((u >> 16) & 1u)) >> 16;
    return (ushort_t)r;
}
__device__ inline float bf2f(ushort_t b) { return __uint_as_float(((unsigned int)b) << 16); }
__device__ inline void stout(float* p, float v) { *p = v; }
__device__ inline void stout(ushort_t* p, float v) { *p = f2bf(v); }
__device__ inline void stout(_Float16* p, float v) { *p = (_Float16)v; }

// ---------------- CSR build ----------------
__global__ __launch_bounds__(256) void k_hist(const int* __restrict__ ei, int* __restrict__ cnt) {
    int e = blockIdx.x * 256 + threadIdx.x;
    if (e < N_EDGES) atomicAdd(&cnt[ei[N_EDGES + e]], 1);
}

__global__ __launch_bounds__(1024) void k_scan(const int* __restrict__ cnt,
                                               int* __restrict__ off, int* __restrict__ cursor) {
    __shared__ int part[1024];
    int t = threadIdx.x;
    int base = t * 10;
    int s = 0;
#pragma unroll
    for (int i = 0; i < 10; i++) {
        int idx = base + i;
        if (idx < N_NODES) s += cnt[idx];
    }
    part[t] = s;
    __syncthreads();
    for (int d = 1; d < 1024; d <<= 1) {
        int v = (t >= d) ? part[t - d] : 0;
        __syncthreads();
        part[t] += v;
        __syncthreads();
    }
    int run = (t == 0) ? 0 : part[t - 1];
#pragma unroll
    for (int i = 0; i < 10; i++) {
        int idx = base + i;
        if (idx < N_NODES) {
            off[idx] = run;
            cursor[idx] = run;
            run += cnt[idx];
        }
    }
    if (t == 0) off[N_NODES] = N_EDGES;
}

__global__ __launch_bounds__(256) void k_scatter(const int* __restrict__ ei, const float* __restrict__ ew,
                                                 int* __restrict__ cursor,
                                                 int* __restrict__ csr_src, float* __restrict__ csr_ew) {
    int e = blockIdx.x * 256 + threadIdx.x;
    if (e < N_EDGES) {
        int d = ei[N_EDGES + e];
        int pos = atomicAdd(&cursor[d], 1);
        csr_src[pos] = ei[e];
        csr_ew[pos] = ew[e];
    }
}

// ---------------- pair bucket sort: fixed-capacity buckets, padded cursors ----------------
__global__ __launch_bounds__(256) void k_pscatter(const int* __restrict__ el, int* __restrict__ gcur,
                                                  int2* __restrict__ sd, int* __restrict__ perm) {
    __shared__ int lcnt[NBUCK2], lbase[NBUCK2], lcur[NBUCK2];
    int t = threadIdx.x;
    if (t < NBUCK2) { lcnt[t] = 0; lcur[t] = 0; }
    __syncthreads();
    for (int i = blockIdx.x * 256 + t; i < N_PAIRS; i += gridDim.x * 256) {
        int s = el[i], d = el[N_PAIRS + i];
        atomicAdd(&lcnt[(s / BUCKW) * NBUCK + d / BUCKW], 1);
    }
    __syncthreads();
    if (t < NBUCK2 && lcnt[t] > 0) lbase[t] = atomicAdd(&gcur[t * 16], lcnt[t]);
    __syncthreads();
    for (int i = blockIdx.x * 256 + t; i < N_PAIRS; i += gridDim.x * 256) {
        int s = el[i], d = el[N_PAIRS + i];
        int b = (s / BUCKW) * NBUCK + d / BUCKW;
        int r = atomicAdd(&lcur[b], 1);
        int pos = b * BCAP + lbase[b] + r;
        sd[pos] = make_int2(s, d);
        perm[pos] = i;
    }
}

// ---------------- weight split+transpose: W[K,NC] fp32 -> Wt_hi [NC,K] bf16 ----------------
__global__ __launch_bounds__(256) void k_wsplit(
    const float* Wr1, const float* Wo1, const float* Wr2, const float* Wo2,
    const float* Wr3, const float* Wo3, const float* Wd1,
    ushort_t* r1h, ushort_t* o1h, ushort_t* r2h, ushort_t* o2h,
    ushort_t* r3h, ushort_t* o3h, ushort_t* dah, ushort_t* dbh) {
    const float* src; ushort_t* dh; int K, NC;
    switch (blockIdx.z) {
        case 0: src = Wr1; dh = r1h; K = 256; NC = 256; break;
        case 1: src = Wo1; dh = o1h; K = 256; NC = 256; break;
        case 2: src = Wr2; dh = r2h; K = 256; NC = 128; break;
        case 3: src = Wo2; dh = o2h; K = 256; NC = 128; break;
        case 4: src = Wr3; dh = r3h; K = 128; NC = 128; break;
        case 5: src = Wo3; dh = o3h; K = 128; NC = 128; break;
        case 6: src = Wd1;             dh = dah; K = 128; NC = 256; break;
        default: src = Wd1 + 128 * 256; dh = dbh; K = 128; NC = 256; break;
    }
    int tk = blockIdx.x * 32, tn = blockIdx.y * 32;
    if (tk >= K || tn >= NC) return;
    __shared__ float tile[32][33];
    int tx = threadIdx.x & 31, ty0 = threadIdx.x >> 5;
#pragma unroll
    for (int r = 0; r < 4; r++) {
        int k = tk + ty0 + r * 8;
        tile[ty0 + r * 8][tx] = src[(size_t)k * NC + tn + tx];
    }
    __syncthreads();
#pragma unroll
    for (int r = 0; r < 4; r++) {
        int n = tn + ty0 + r * 8;
        dh[(size_t)n * K + tk + tx] = f2bf(tile[tx][ty0 + r * 8]);
    }
}

// ---------------- x convert: fp32 -> bf16 (hi only; layer-1 GEMM is plain bf16) ----------------
__global__ __launch_bounds__(256) void k_xsplit(const float* __restrict__ x,
                                                ushort_t* __restrict__ xh, int n4) {
    int i = blockIdx.x * 256 + threadIdx.x;
    if (i >= n4) return;
    float4 f = ((const float4*)x)[i];
    union { uint2 v; ushort_t u[4]; } H;
    H.u[0] = f2bf(f.x); H.u[1] = f2bf(f.y); H.u[2] = f2bf(f.z); H.u[3] = f2bf(f.w);
    ((uint2*)xh)[i] = H.v;
}

// ---------------- fused agg epilogue: h = act(agg(P) + R + bias) -> bf16 hi (+lo opt) ----------------
template <int C, bool RELU, bool EMITLO>
__global__ __launch_bounds__(256) void k_aggf(const ushort_t* __restrict__ P, const float* __restrict__ R,
                                              const float* __restrict__ bias,
                                              const int* __restrict__ off, const int* __restrict__ csr_src,
                                              const float* __restrict__ csr_ew,
                                              ushort_t* __restrict__ hh, ushort_t* __restrict__ hl) {
    int wave = (blockIdx.x * 256 + threadIdx.x) >> 6;
    int lane = threadIdx.x & 63;
    if (wave >= N_NODES) return;
    int beg = off[wave], end = off[wave + 1];
    if constexpr (C == 256) {
        int col = lane * 4;
        float4 acc = {0.f, 0.f, 0.f, 0.f};
        int e = beg;
        for (; e + 1 < end; e += 2) {
            int s0 = csr_src[e], s1 = csr_src[e + 1];
            float w0 = csr_ew[e], w1 = csr_ew[e + 1];
            uint2 u0 = *(const uint2*)&P[(size_t)s0 * 256 + col];
            uint2 u1 = *(const uint2*)&P[(size_t)s1 * 256 + col];
            acc.x += w0 * blo(u0.x) + w1 * blo(u1.x);
            acc.y += w0 * bhi(u0.x) + w1 * bhi(u1.x);
            acc.z += w0 * blo(u0.y) + w1 * blo(u1.y);
            acc.w += w0 * bhi(u0.y) + w1 * bhi(u1.y);
        }
        if (e < end) {
            int s0 = csr_src[e];
            float w0 = csr_ew[e];
            uint2 u0 = *(const uint2*)&P[(size_t)s0 * 256 + col];
            acc.x += w0 * blo(u0.x); acc.y += w0 * bhi(u0.x);
            acc.z += w0 * blo(u0.y); acc.w += w0 * bhi(u0.y);
        }
        float4 rr = *(const float4*)&R[(size_t)wave * 256 + col];
        float4 bb = *(const float4*)&bias[col];
        float o[4];
        o[0] = acc.x + rr.x + bb.x; o[1] = acc.y + rr.y + bb.y;
        o[2] = acc.z + rr.z + bb.z; o[3] = acc.w + rr.w + bb.w;
        if (RELU) {
#pragma unroll
            for (int j = 0; j < 4; j++) o[j] = fmaxf(o[j], 0.f);
        }
        union { uint2 v; ushort_t u[4]; } H, L;
#pragma unroll
        for (int j = 0; j < 4; j++) {
            ushort_t h = f2bf(o[j]);
            H.u[j] = h;
            if (EMITLO) L.u[j] = f2bf(o[j] - bf2f(h));
        }
        *(uint2*)&hh[(size_t)wave * 256 + col] = H.v;
        if (EMITLO) *(uint2*)&hl[(size_t)wave * 256 + col] = L.v;
    } else {
        int col = lane * 2;
        float2 acc = {0.f, 0.f};
        int e = beg;
        for (; e + 1 < end; e += 2) {
            int s0 = csr_src[e], s1 = csr_src[e + 1];
            float w0 = csr_ew[e], w1 = csr_ew[e + 1];
            unsigned int u0 = *(const unsigned int*)&P[(size_t)s0 * 128 + col];
            unsigned int u1 = *(const unsigned int*)&P[(size_t)s1 * 128 + col];
            acc.x += w0 * blo(u0) + w1 * blo(u1);
            acc.y += w0 * bhi(u0) + w1 * bhi(u1);
        }
        if (e < end) {
            int s0 = csr_src[e];
            float w0 = csr_ew[e];
            unsigned int u0 = *(const unsigned int*)&P[(size_t)s0 * 128 + col];
            acc.x += w0 * blo(u0); acc.y += w0 * bhi(u0);
        }
        float2 rr = *(const float2*)&R[(size_t)wave * 128 + col];
        float2 bb = *(const float2*)&bias[col];
        float o0 = acc.x + rr.x + bb.x, o1 = acc.y + rr.y + bb.y;
        if (RELU) { o0 = fmaxf(o0, 0.f); o1 = fmaxf(o1, 0.f); }
        union { unsigned int v; ushort_t u[2]; } H, L;
        ushort_t h0 = f2bf(o0), h1 = f2bf(o1);
        H.u[0] = h0; H.u[1] = h1;
        *(unsigned int*)&hh[(size_t)wave * 128 + col] = H.v;
        if (EMITLO) {
            L.u[0] = f2bf(o0 - bf2f(h0)); L.u[1] = f2bf(o1 - bf2f(h1));
            *(unsigned int*)&hl[(size_t)wave * 128 + col] = L.v;
        }
    }
}

// ---------------- MFMA dual-GEMM: A bf16 (hi, + optional lo), W hi bf16 [NC,K] ----------------
template <bool ALO, typename T1, typename T2>
__global__ __launch_bounds__(256) void k_gemm_bf(const ushort_t* __restrict__ Ahi, const ushort_t* __restrict__ Alo,
                                                 const ushort_t* __restrict__ W1hi, const ushort_t* __restrict__ W2hi,
                                                 const float* __restrict__ bias1,
                                                 T1* __restrict__ out1, T2* __restrict__ out2,
                                                 int M, int K, int NC) {
    __shared__ ushort_t sAh[64][32], sAl[ALO ? 64 : 1][32];
    __shared__ ushort_t s1h[64][32], s2h[64][32];

    int tid = threadIdx.x;
    int lane = tid & 63, wid = tid >> 6;
    int wm = wid >> 1, wn = wid & 1;
    int l15 = lane & 15, quad = lane >> 4;
    int row0 = blockIdx.x * 64, col0 = blockIdx.y * 64;

    int srow = tid >> 2, schunk = (tid & 3) * 8;
    int arow = row0 + srow; if (arow > M - 1) arow = M - 1;
    const ushort_t* gAh = Ahi + (size_t)arow * K + schunk;
    const ushort_t* gAl = Alo + (size_t)arow * K + schunk;
    int wrow = col0 + srow;
    const ushort_t* g1h = W1hi + (size_t)wrow * K + schunk;
    const ushort_t* g2h = W2hi + (size_t)wrow * K + schunk;

    floatx4 acc1[2][2] = {}, acc2[2][2] = {};

    for (int kk = 0; kk < K; kk += 32) {
        *(short8*)&sAh[srow][schunk] = *(const short8*)(gAh + kk);
        if (ALO) *(short8*)&sAl[srow][schunk] = *(const short8*)(gAl + kk);
        *(short8*)&s1h[srow][schunk] = *(const short8*)(g1h + kk);
        *(short8*)&s2h[srow][schunk] = *(const short8*)(g2h + kk);
        __syncthreads();

        short8 ah[2], al[2], b1h[2], b2h[2];
#pragma unroll
        for (int t = 0; t < 2; t++) {
            int ar = wm * 32 + t * 16 + l15;
            ah[t] = *(const short8*)&sAh[ar][quad * 8];
            if (ALO) al[t] = *(const short8*)&sAl[ar][quad * 8];
            int bc = wn * 32 + t * 16 + l15;
            b1h[t] = *(const short8*)&s1h[bc][quad * 8];
            b2h[t] = *(const short8*)&s2h[bc][quad * 8];
        }
#pragma unroll
        for (int tm = 0; tm < 2; tm++)
#pragma unroll
            for (int tn = 0; tn < 2; tn++) {
                acc1[tm][tn] = __builtin_amdgcn_mfma_f32_16x16x32_bf16(ah[tm], b1h[tn], acc1[tm][tn], 0, 0, 0);
                acc2[tm][tn] = __builtin_amdgcn_mfma_f32_16x16x32_bf16(ah[tm], b2h[tn], acc2[tm][tn], 0, 0, 0);
                if (ALO) {
                    acc1[tm][tn] = __builtin_amdgcn_mfma_f32_16x16x32_bf16(al[tm], b1h[tn], acc1[tm][tn], 0, 0, 0);
                    acc2[tm][tn] = __builtin_amdgcn_mfma_f32_16x16x32_bf16(al[tm], b2h[tn], acc2[tm][tn], 0, 0, 0);
                }
            }
        __syncthreads();
    }

    // C/D layout: col = lane&15, row = quad*4 + reg
#pragma unroll
    for (int tm = 0; tm < 2; tm++) {
#pragma unroll
        for (int tn = 0; tn < 2; tn++) {
            int gc = col0 + wn * 32 + tn * 16 + l15;
            float bv = bias1 ? bias1[gc] : 0.f;
#pragma unroll
            for (int reg = 0; reg < 4; reg++) {
                int gr = row0 + wm * 32 + tm * 16 + quad * 4 + reg;
                if (gr >= M) continue;
                stout(&out1[(size_t)gr * NC + gc], acc1[tm][tn][reg] + bv);
                stout(&out2[(size_t)gr * NC + gc], acc2[tm][tn][reg]);
            }
        }
    }
}

// ---------------- decoder: 8 lanes per pair, 8 pairs/wave, f16 packed dot ----------------
__global__ __launch_bounds__(256) void k_decoder(const _Float16* __restrict__ Ab, const _Float16* __restrict__ Bb,
                                                 const int2* __restrict__ sd, const int* __restrict__ perm,
                                                 const int* __restrict__ gcur,
                                                 const float* __restrict__ Wd2, const float* __restrict__ bd2,
                                                 float* __restrict__ out) {
    int x = blockIdx.x & 7;          // XCD-affine s-bucket group
    int j = blockIdx.x >> 3;         // slice within group
    int J = gridDim.x >> 3;
    int w = threadIdx.x >> 6;        // wave in block (0..3)
    int lane = threadIdx.x & 63;
    int g = lane >> 3, l8 = lane & 7;  // 8 groups of 8 lanes; lane owns 32 channels
    int col = l8 * 32;
    half2_t w2p[16];
#pragma unroll
    for (int q = 0; q < 16; q++) {
        half2_t t = {(_Float16)Wd2[col + 2 * q], (_Float16)Wd2[col + 2 * q + 1]};
        w2p[q] = t;
    }
    const half2_t z = {(_Float16)0.f, (_Float16)0.f};
    float b2 = bd2[0];
    for (int db = 0; db < NBUCK; db++) {
        int bi = x * NBUCK + db;
        int R0 = bi * BCAP;
        int len = gcur[bi * 16];
        int s0 = (int)((long)len * j / J);
        int s1 = (int)((long)len * (j + 1) / J);
        int beg = R0 + s0, end = R0 + s1;
        for (int i0 = beg + w * 8; i0 < end; i0 += 32) {
            int p = i0 + g;
            bool act = p < end;
            int pc = act ? p : end - 1;   // clamp inactive groups to valid pair
            int2 pd = sd[pc];
            const uint4* arow = (const uint4*)&Ab[(size_t)pd.x * 256 + col];
            const uint4* brow = (const uint4*)&Bb[(size_t)pd.y * 256 + col];
            uint4 a0 = arow[0], a1 = arow[1], a2 = arow[2], a3 = arow[3];
            uint4 b0 = brow[0], b1 = brow[1], b2v = brow[2], b3 = brow[3];
            float r = 0.f;
            half2_t s;
#define ACC8(ua, ub, qb)                                                                       \
            s = __builtin_elementwise_max(__builtin_bit_cast(half2_t, ua.x) + __builtin_bit_cast(half2_t, ub.x), z); \
            r = __builtin_amdgcn_fdot2(s, w2p[qb + 0], r, false);                              \
            s = __builtin_elementwise_max(__builtin_bit_cast(half2_t, ua.y) + __builtin_bit_cast(half2_t, ub.y), z); \
            r = __builtin_amdgcn_fdot2(s, w2p[qb + 1], r, false);                              \
            s = __builtin_elementwise_max(__builtin_bit_cast(half2_t, ua.z) + __builtin_bit_cast(half2_t, ub.z), z); \
            r = __builtin_amdgcn_fdot2(s, w2p[qb + 2], r, false);                              \
            s = __builtin_elementwise_max(__builtin_bit_cast(half2_t, ua.w) + __builtin_bit_cast(half2_t, ub.w), z); \
            r = __builtin_amdgcn_fdot2(s, w2p[qb + 3], r, false);
            ACC8(a0, b0, 0)
            ACC8(a1, b1, 4)
            ACC8(a2, b2v, 8)
            ACC8(a3, b3, 12)
#undef ACC8
            r += __shfl_down(r, 4, 8);
            r += __shfl_down(r, 2, 8);
            r += __shfl_down(r, 1, 8);
            if (l8 == 0 && act) out[perm[p]] = r + b2;
        }
    }
}

extern "C" void kernel_launch(void* const* d_in, const int* in_sizes, int n_in,
                              void* d_out, int out_size, void* d_ws, size_t ws_size,
                              hipStream_t stream) {
    const float* x   = (const float*)d_in[0];
    const int*   ei  = (const int*)d_in[1];
    const float* ew  = (const float*)d_in[2];
    const int*   el  = (const int*)d_in[3];
    const float* Wr1 = (const float*)d_in[4];
    const float* br1 = (const float*)d_in[5];
    const float* Wo1 = (const float*)d_in[6];
    const float* Wr2 = (const float*)d_in[7];
    const float* br2 = (const float*)d_in[8];
    const float* Wo2 = (const float*)d_in[9];
    const float* Wr3 = (const float*)d_in[10];
    const float* br3 = (const float*)d_in[11];
    const float* Wo3 = (const float*)d_in[12];
    const float* Wd1 = (const float*)d_in[13];
    const float* bd1 = (const float*)d_in[14];
    const float* Wd2 = (const float*)d_in[15];
    const float* bd2 = (const float*)d_in[16];
    float* out = (float*)d_out;

    char* ws = (char*)d_ws;
    size_t o = 0;
    auto alloc = [&](size_t bytes) { size_t p = o; o += (bytes + 255) & ~(size_t)255; return (void*)(ws + p); };
    // cnt + gcur adjacent -> single memset
    int*     cnt     = (int*)alloc(N_NODES * 4);
    int*     gcur    = (int*)alloc(NBUCK2 * 16 * 4);
    size_t   zero_bytes = (size_t)((char*)gcur - (char*)cnt) + NBUCK2 * 16 * 4;
    int*     cursor  = (int*)alloc(N_NODES * 4);
    int*     off     = (int*)alloc((N_NODES + 1) * 4);
    int*     csr_src = (int*)alloc(N_EDGES * 4);
    float*   csr_ew  = (float*)alloc(N_EDGES * 4);
    int2*    psd     = (int2*)alloc((size_t)NBUCK2 * BCAP * 8);
    int*     pperm   = (int*)alloc((size_t)NBUCK2 * BCAP * 4);
    // activation buffers (hi always; lo only used for z)
    ushort_t* ash = (ushort_t*)alloc((size_t)N_NODES * 256 * 2);
    ushort_t* asl = (ushort_t*)alloc((size_t)N_NODES * 256 * 2);
    // GEMM outputs: P bf16 (later Atab f16), R fp32 (later Btab f16)
    ushort_t* Pb  = (ushort_t*)alloc((size_t)N_NODES * 256 * 2);
    float*    Rb  = (float*)alloc((size_t)N_NODES * 256 * 4);
    // pre-split transposed weights (hi only)
    ushort_t* r1h = (ushort_t*)alloc(256 * 256 * 2);
    ushort_t* o1h = (ushort_t*)alloc(256 * 256 * 2);
    ushort_t* r2h = (ushort_t*)alloc(128 * 256 * 2);
    ushort_t* o2h = (ushort_t*)alloc(128 * 256 * 2);
    ushort_t* r3h = (ushort_t*)alloc(128 * 128 * 2);
    ushort_t* o3h = (ushort_t*)alloc(128 * 128 * 2);
    ushort_t* dah = (ushort_t*)alloc(256 * 128 * 2);
    ushort_t* dbh = (ushort_t*)alloc(256 * 128 * 2);
    _Float16* Atab = (_Float16*)Pb;
    _Float16* Btab = (_Float16*)Rb;

    hipMemsetAsync(cnt, 0, zero_bytes, stream);

    // pre-split weights + x
    {
        dim3 g(8, 8, 8);
        k_wsplit<<<g, 256, 0, stream>>>(Wr1, Wo1, Wr2, Wo2, Wr3, Wo3, Wd1,
                                        r1h, o1h, r2h, o2h, r3h, o3h, dah, dbh);
    }
    k_xsplit<<<(N_NODES * 256 / 4 + 255) / 256, 256, 0, stream>>>(x, ash, N_NODES * 256 / 4);

    // CSR build (edges by dst)
    k_hist<<<(N_EDGES + 255) / 256, 256, 0, stream>>>(ei, cnt);
    k_scan<<<1, 1024, 0, stream>>>(cnt, off, cursor);
    k_scatter<<<(N_EDGES + 255) / 256, 256, 0, stream>>>(ei, ew, cursor, csr_src, csr_ew);

    // pair bucket sort
    k_pscatter<<<512, 256, 0, stream>>>(el, gcur, psd, pperm);

    const int AGG_BLOCKS = (N_NODES + 3) / 4;
    const int GX = (N_NODES + 63) / 64;

    // Layer 1 (plain bf16 A)
    k_gemm_bf<false, ushort_t, float><<<dim3(GX, 4), 256, 0, stream>>>(ash, asl, r1h, o1h, nullptr,
                                                                       Pb, Rb, N_NODES, 256, 256);
    k_aggf<256, true, false><<<AGG_BLOCKS, 256, 0, stream>>>(Pb, Rb, br1, off, csr_src, csr_ew, ash, asl);

    // Layer 2 (plain bf16 A)
    k_gemm_bf<false, ushort_t, float><<<dim3(GX, 2), 256, 0, stream>>>(ash, asl, r2h, o2h, nullptr,
                                                                       Pb, Rb, N_NODES, 256, 128);
    k_aggf<128, true, false><<<AGG_BLOCKS, 256, 0, stream>>>(Pb, Rb, br2, off, csr_src, csr_ew, ash, asl);

    // Layer 3 (plain bf16 A; emit z as hi/lo for decoder-table GEMM)
    k_gemm_bf<false, ushort_t, float><<<dim3(GX, 2), 256, 0, stream>>>(ash, asl, r3h, o3h, nullptr,
                                                                       Pb, Rb, N_NODES, 128, 128);
    k_aggf<128, false, true><<<AGG_BLOCKS, 256, 0, stream>>>(Pb, Rb, br3, off, csr_src, csr_ew, ash, asl);

    // Decoder tables (f16): Atab = z@Wd1_top + bd1, Btab = z@Wd1_bot  (A = z hi/lo)
    k_gemm_bf<true, _Float16, _Float16><<<dim3(GX, 4), 256, 0, stream>>>(ash, asl, dah, dbh, bd1,
                                                                         Atab, Btab, N_NODES, 128, 256);

    // Decoder (bucket-sorted, XCD-affine, 8 lanes/pair)
    k_decoder<<<2048, 256, 0, stream>>>(Atab, Btab, psd, pperm, gcur, Wd2, bd2, out);
}

// Round 10
// 358.617 us; speedup vs baseline: 1.0686x; 1.0686x over previous
//
#include <hip/hip_runtime.h>

#define N_NODES 10000
#define N_EDGES 320000
#define N_PAIRS 1000000
#define NBUCK 8
#define NBUCK2 64
#define BUCKW 1250   // N_NODES / 8
#define BCAP 17408   // per-bucket capacity (expected 15625, sigma~124)

typedef unsigned short ushort_t;
typedef __attribute__((ext_vector_type(8))) short short8;
typedef __attribute__((ext_vector_type(4))) float floatx4;
typedef _Float16 half2_t __attribute__((ext_vector_type(2)));

__device__ inline float blo(unsigned int u) { return __uint_as_float(u << 16); }
__device__ inline float bhi(unsigned int u) { return __uint_as_float(u & 0xffff0000u); }
__device__ inline ushort_t f2bf(float f) {
    unsigned int u = __float_as_uint(f);
    unsigned int r = (u + 0x7fffu + ((u >> 16) & 1u)) >> 16;
    return (ushort_t)r;
}
__device__ inline float bf2f(ushort_t b) { return __uint_as_float(((unsigned int)b) << 16); }
__device__ inline void stout(float* p, float v) { *p = v; }
__device__ inline void stout(ushort_t* p, float v) { *p = f2bf(v); }
__device__ inline void stout(_Float16* p, float v) { *p = (_Float16)v; }

// ---------------- CSR build ----------------
__global__ __launch_bounds__(256) void k_hist(const int* __restrict__ ei, int* __restrict__ cnt) {
    int e = blockIdx.x * 256 + threadIdx.x;
    if (e < N_EDGES) atomicAdd(&cnt[ei[N_EDGES + e]], 1);
}

__global__ __launch_bounds__(1024) void k_scan(const int* __restrict__ cnt,
                                               int* __restrict__ off, int* __restrict__ cursor) {
    __shared__ int part[1024];
    int t = threadIdx.x;
    int base = t * 10;
    int s = 0;
#pragma unroll
    for (int i = 0; i < 10; i++) {
        int idx = base + i;
        if (idx < N_NODES) s += cnt[idx];
    }
    part[t] = s;
    __syncthreads();
    for (int d = 1; d < 1024; d <<= 1) {
        int v = (t >= d) ? part[t - d] : 0;
        __syncthreads();
        part[t] += v;
        __syncthreads();
    }
    int run = (t == 0) ? 0 : part[t - 1];
#pragma unroll
    for (int i = 0; i < 10; i++) {
        int idx = base + i;
        if (idx < N_NODES) {
            off[idx] = run;
            cursor[idx] = run;
            run += cnt[idx];
        }
    }
    if (t == 0) off[N_NODES] = N_EDGES;
}

__global__ __launch_bounds__(256) void k_scatter(const int* __restrict__ ei, const float* __restrict__ ew,
                                                 int* __restrict__ cursor,
                                                 int* __restrict__ csr_src, float* __restrict__ csr_ew) {
    int e = blockIdx.x * 256 + threadIdx.x;
    if (e < N_EDGES) {
        int d = ei[N_EDGES + e];
        int pos = atomicAdd(&cursor[d], 1);
        csr_src[pos] = ei[e];
        csr_ew[pos] = ew[e];
    }
}

// ---------------- pair bucket sort: fixed-capacity buckets, padded cursors ----------------
__global__ __launch_bounds__(256) void k_pscatter(const int* __restrict__ el, int* __restrict__ gcur,
                                                  int2* __restrict__ sd, int* __restrict__ perm) {
    __shared__ int lcnt[NBUCK2], lbase[NBUCK2], lcur[NBUCK2];
    int t = threadIdx.x;
    if (t < NBUCK2) { lcnt[t] = 0; lcur[t] = 0; }
    __syncthreads();
    for (int i = blockIdx.x * 256 + t; i < N_PAIRS; i += gridDim.x * 256) {
        int s = el[i], d = el[N_PAIRS + i];
        atomicAdd(&lcnt[(s / BUCKW) * NBUCK + d / BUCKW], 1);
    }
    __syncthreads();
    if (t < NBUCK2 && lcnt[t] > 0) lbase[t] = atomicAdd(&gcur[t * 16], lcnt[t]);
    __syncthreads();
    for (int i = blockIdx.x * 256 + t; i < N_PAIRS; i += gridDim.x * 256) {
        int s = el[i], d = el[N_PAIRS + i];
        int b = (s / BUCKW) * NBUCK + d / BUCKW;
        int r = atomicAdd(&lcur[b], 1);
        int pos = b * BCAP + lbase[b] + r;
        sd[pos] = make_int2(s, d);
        perm[pos] = i;
    }
}

// ---------------- weight split+transpose: W[K,NC] fp32 -> Wt_hi [NC,K] bf16 ----------------
__global__ __launch_bounds__(256) void k_wsplit(
    const float* Wr1, const float* Wo1, const float* Wr2, const float* Wo2,
    const float* Wr3, const float* Wo3, const float* Wd1,
    ushort_t* r1h, ushort_t* o1h, ushort_t* r2h, ushort_t* o2h,
    ushort_t* r3h, ushort_t* o3h, ushort_t* dah, ushort_t* dbh) {
    const float* src; ushort_t* dh; int K, NC;
    switch (blockIdx.z) {
        case 0: src = Wr1; dh = r1h; K = 256; NC = 256; break;
        case 1: src = Wo1; dh = o1h; K = 256; NC = 256; break;
        case 2: src = Wr2; dh = r2h; K = 256; NC = 128; break;
        case 3: src = Wo2; dh = o2h; K = 256; NC = 128; break;
        case 4: src = Wr3; dh = r3h; K = 128; NC = 128; break;
        case 5: src = Wo3; dh = o3h; K = 128; NC = 128; break;
        case 6: src = Wd1;             dh = dah; K = 128; NC = 256; break;
        default: src = Wd1 + 128 * 256; dh = dbh; K = 128; NC = 256; break;
    }
    int tk = blockIdx.x * 32, tn = blockIdx.y * 32;
    if (tk >= K || tn >= NC) return;
    __shared__ float tile[32][33];
    int tx = threadIdx.x & 31, ty0 = threadIdx.x >> 5;
#pragma unroll
    for (int r = 0; r < 4; r++) {
        int k = tk + ty0 + r * 8;
        tile[ty0 + r * 8][tx] = src[(size_t)k * NC + tn + tx];
    }
    __syncthreads();
#pragma unroll
    for (int r = 0; r < 4; r++) {
        int n = tn + ty0 + r * 8;
        dh[(size_t)n * K + tk + tx] = f2bf(tile[tx][ty0 + r * 8]);
    }
}

// ---------------- x convert: fp32 -> bf16 (hi only) ----------------
__global__ __launch_bounds__(256) void k_xsplit(const float* __restrict__ x,
                                                ushort_t* __restrict__ xh, int n4) {
    int i = blockIdx.x * 256 + threadIdx.x;
    if (i >= n4) return;
    float4 f = ((const float4*)x)[i];
    union { uint2 v; ushort_t u[4]; } H;
    H.u[0] = f2bf(f.x); H.u[1] = f2bf(f.y); H.u[2] = f2bf(f.z); H.u[3] = f2bf(f.w);
    ((uint2*)xh)[i] = H.v;
}

// ---------------- fused agg epilogue: h = act(agg(P) + R + bias) -> bf16 hi (+lo opt) ----------------
template <int C, bool RELU, bool EMITLO>
__global__ __launch_bounds__(256) void k_aggf(const ushort_t* __restrict__ P, const float* __restrict__ R,
                                              const float* __restrict__ bias,
                                              const int* __restrict__ off, const int* __restrict__ csr_src,
                                              const float* __restrict__ csr_ew,
                                              ushort_t* __restrict__ hh, ushort_t* __restrict__ hl) {
    int wave = (blockIdx.x * 256 + threadIdx.x) >> 6;
    int lane = threadIdx.x & 63;
    if (wave >= N_NODES) return;
    int beg = off[wave], end = off[wave + 1];
    if constexpr (C == 256) {
        int col = lane * 4;
        float4 acc = {0.f, 0.f, 0.f, 0.f};
        int e = beg;
        for (; e + 1 < end; e += 2) {
            int s0 = csr_src[e], s1 = csr_src[e + 1];
            float w0 = csr_ew[e], w1 = csr_ew[e + 1];
            uint2 u0 = *(const uint2*)&P[(size_t)s0 * 256 + col];
            uint2 u1 = *(const uint2*)&P[(size_t)s1 * 256 + col];
            acc.x += w0 * blo(u0.x) + w1 * blo(u1.x);
            acc.y += w0 * bhi(u0.x) + w1 * bhi(u1.x);
            acc.z += w0 * blo(u0.y) + w1 * blo(u1.y);
            acc.w += w0 * bhi(u0.y) + w1 * bhi(u1.y);
        }
        if (e < end) {
            int s0 = csr_src[e];
            float w0 = csr_ew[e];
            uint2 u0 = *(const uint2*)&P[(size_t)s0 * 256 + col];
            acc.x += w0 * blo(u0.x); acc.y += w0 * bhi(u0.x);
            acc.z += w0 * blo(u0.y); acc.w += w0 * bhi(u0.y);
        }
        float4 rr = *(const float4*)&R[(size_t)wave * 256 + col];
        float4 bb = *(const float4*)&bias[col];
        float o[4];
        o[0] = acc.x + rr.x + bb.x; o[1] = acc.y + rr.y + bb.y;
        o[2] = acc.z + rr.z + bb.z; o[3] = acc.w + rr.w + bb.w;
        if (RELU) {
#pragma unroll
            for (int j = 0; j < 4; j++) o[j] = fmaxf(o[j], 0.f);
        }
        union { uint2 v; ushort_t u[4]; } H, L;
#pragma unroll
        for (int j = 0; j < 4; j++) {
            ushort_t h = f2bf(o[j]);
            H.u[j] = h;
            if (EMITLO) L.u[j] = f2bf(o[j] - bf2f(h));
        }
        *(uint2*)&hh[(size_t)wave * 256 + col] = H.v;
        if (EMITLO) *(uint2*)&hl[(size_t)wave * 256 + col] = L.v;
    } else {
        int col = lane * 2;
        float2 acc = {0.f, 0.f};
        int e = beg;
        for (; e + 1 < end; e += 2) {
            int s0 = csr_src[e], s1 = csr_src[e + 1];
            float w0 = csr_ew[e], w1 = csr_ew[e + 1];
            unsigned int u0 = *(const unsigned int*)&P[(size_t)s0 * 128 + col];
            unsigned int u1 = *(const unsigned int*)&P[(size_t)s1 * 128 + col];
            acc.x += w0 * blo(u0) + w1 * blo(u1);
            acc.y += w0 * bhi(u0) + w1 * bhi(u1);
        }
        if (e < end) {
            int s0 = csr_src[e];
            float w0 = csr_ew[e];
            unsigned int u0 = *(const unsigned int*)&P[(size_t)s0 * 128 + col];
            acc.x += w0 * blo(u0); acc.y += w0 * bhi(u0);
        }
        float2 rr = *(const float2*)&R[(size_t)wave * 128 + col];
        float2 bb = *(const float2*)&bias[col];
        float o0 = acc.x + rr.x + bb.x, o1 = acc.y + rr.y + bb.y;
        if (RELU) { o0 = fmaxf(o0, 0.f); o1 = fmaxf(o1, 0.f); }
        union { unsigned int v; ushort_t u[2]; } H, L;
        ushort_t h0 = f2bf(o0), h1 = f2bf(o1);
        H.u[0] = h0; H.u[1] = h1;
        *(unsigned int*)&hh[(size_t)wave * 128 + col] = H.v;
        if (EMITLO) {
            L.u[0] = f2bf(o0 - bf2f(h0)); L.u[1] = f2bf(o1 - bf2f(h1));
            *(unsigned int*)&hl[(size_t)wave * 128 + col] = L.v;
        }
    }
}

// ---------------- MFMA dual-GEMM: A bf16 (hi, + optional lo), W hi bf16 [NC,K] ----------------
template <bool ALO, typename T1, typename T2>
__global__ __launch_bounds__(256) void k_gemm_bf(const ushort_t* __restrict__ Ahi, const ushort_t* __restrict__ Alo,
                                                 const ushort_t* __restrict__ W1hi, const ushort_t* __restrict__ W2hi,
                                                 const float* __restrict__ bias1,
                                                 T1* __restrict__ out1, T2* __restrict__ out2,
                                                 int M, int K, int NC) {
    __shared__ ushort_t sAh[64][32], sAl[ALO ? 64 : 1][32];
    __shared__ ushort_t s1h[64][32], s2h[64][32];

    int tid = threadIdx.x;
    int lane = tid & 63, wid = tid >> 6;
    int wm = wid >> 1, wn = wid & 1;
    int l15 = lane & 15, quad = lane >> 4;
    int row0 = blockIdx.x * 64, col0 = blockIdx.y * 64;

    int srow = tid >> 2, schunk = (tid & 3) * 8;
    int arow = row0 + srow; if (arow > M - 1) arow = M - 1;
    const ushort_t* gAh = Ahi + (size_t)arow * K + schunk;
    const ushort_t* gAl = Alo + (size_t)arow * K + schunk;
    int wrow = col0 + srow;
    const ushort_t* g1h = W1hi + (size_t)wrow * K + schunk;
    const ushort_t* g2h = W2hi + (size_t)wrow * K + schunk;

    floatx4 acc1[2][2] = {}, acc2[2][2] = {};

    for (int kk = 0; kk < K; kk += 32) {
        *(short8*)&sAh[srow][schunk] = *(const short8*)(gAh + kk);
        if (ALO) *(short8*)&sAl[srow][schunk] = *(const short8*)(gAl + kk);
        *(short8*)&s1h[srow][schunk] = *(const short8*)(g1h + kk);
        *(short8*)&s2h[srow][schunk] = *(const short8*)(g2h + kk);
        __syncthreads();

        short8 ah[2], al[2], b1h[2], b2h[2];
#pragma unroll
        for (int t = 0; t < 2; t++) {
            int ar = wm * 32 + t * 16 + l15;
            ah[t] = *(const short8*)&sAh[ar][quad * 8];
            if (ALO) al[t] = *(const short8*)&sAl[ar][quad * 8];
            int bc = wn * 32 + t * 16 + l15;
            b1h[t] = *(const short8*)&s1h[bc][quad * 8];
            b2h[t] = *(const short8*)&s2h[bc][quad * 8];
        }
#pragma unroll
        for (int tm = 0; tm < 2; tm++)
#pragma unroll
            for (int tn = 0; tn < 2; tn++) {
                acc1[tm][tn] = __builtin_amdgcn_mfma_f32_16x16x32_bf16(ah[tm], b1h[tn], acc1[tm][tn], 0, 0, 0);
                acc2[tm][tn] = __builtin_amdgcn_mfma_f32_16x16x32_bf16(ah[tm], b2h[tn], acc2[tm][tn], 0, 0, 0);
                if (ALO) {
                    acc1[tm][tn] = __builtin_amdgcn_mfma_f32_16x16x32_bf16(al[tm], b1h[tn], acc1[tm][tn], 0, 0, 0);
                    acc2[tm][tn] = __builtin_amdgcn_mfma_f32_16x16x32_bf16(al[tm], b2h[tn], acc2[tm][tn], 0, 0, 0);
                }
            }
        __syncthreads();
    }

    // C/D layout: col = lane&15, row = quad*4 + reg
#pragma unroll
    for (int tm = 0; tm < 2; tm++) {
#pragma unroll
        for (int tn = 0; tn < 2; tn++) {
            int gc = col0 + wn * 32 + tn * 16 + l15;
            float bv = bias1 ? bias1[gc] : 0.f;
#pragma unroll
            for (int reg = 0; reg < 4; reg++) {
                int gr = row0 + wm * 32 + tm * 16 + quad * 4 + reg;
                if (gr >= M) continue;
                stout(&out1[(size_t)gr * NC + gc], acc1[tm][tn][reg] + bv);
                stout(&out2[(size_t)gr * NC + gc], acc2[tm][tn][reg]);
            }
        }
    }
}

// ---------------- decoder: half-wave per pair, 4 pairs per iteration, f16 packed dot ----------------
__device__ inline float dot8relu_f16(uint4 ua, uint4 ub, const half2_t* w2p) {
    half2_t z = {(_Float16)0.f, (_Float16)0.f};
    float r = 0.f;
    half2_t s;
    s = __builtin_elementwise_max(__builtin_bit_cast(half2_t, ua.x) + __builtin_bit_cast(half2_t, ub.x), z);
    r = __builtin_amdgcn_fdot2(s, w2p[0], r, false);
    s = __builtin_elementwise_max(__builtin_bit_cast(half2_t, ua.y) + __builtin_bit_cast(half2_t, ub.y), z);
    r = __builtin_amdgcn_fdot2(s, w2p[1], r, false);
    s = __builtin_elementwise_max(__builtin_bit_cast(half2_t, ua.z) + __builtin_bit_cast(half2_t, ub.z), z);
    r = __builtin_amdgcn_fdot2(s, w2p[2], r, false);
    s = __builtin_elementwise_max(__builtin_bit_cast(half2_t, ua.w) + __builtin_bit_cast(half2_t, ub.w), z);
    r = __builtin_amdgcn_fdot2(s, w2p[3], r, false);
    return r;
}

__global__ __launch_bounds__(256) void k_decoder(const _Float16* __restrict__ Ab, const _Float16* __restrict__ Bb,
                                                 const int2* __restrict__ sd, const int* __restrict__ perm,
                                                 const int* __restrict__ gcur,
                                                 const float* __restrict__ Wd2, const float* __restrict__ bd2,
                                                 float* __restrict__ out) {
    int x = blockIdx.x & 7;          // XCD-affine s-bucket group
    int j = blockIdx.x >> 3;         // slice within group
    int J = gridDim.x >> 3;
    int hw = threadIdx.x >> 5;       // half-wave id in block (0..7)
    int l32 = threadIdx.x & 31;
    int col = l32 * 8;
    half2_t w2p[4];
#pragma unroll
    for (int q = 0; q < 4; q++) {
        half2_t t = {(_Float16)Wd2[col + 2 * q], (_Float16)Wd2[col + 2 * q + 1]};
        w2p[q] = t;
    }
    float b2 = bd2[0];
    for (int db = 0; db < NBUCK; db++) {
        int bi = x * NBUCK + db;
        int R0 = bi * BCAP;   // multiple of 4
        int len = gcur[bi * 16];
        int s0 = (int)((long)len * j / J) & ~3;
        int s1 = (j + 1 == J) ? len : ((int)((long)len * (j + 1) / J) & ~3);
        int beg = R0 + s0, end = R0 + s1;
        for (int i0 = beg + hw * 4; i0 < end; i0 += 32) {
            int rem = end - i0;  // >= 1
            // i0 is a multiple of 4 -> 16B-aligned int4 loads; reads past 'end' stay
            // inside this bucket's capacity region (len < BCAP-4), contents clamped below.
            int4 pA = *(const int4*)&sd[i0];
            int4 pB = *(const int4*)&sd[i0 + 2];
            int4 pm = *(const int4*)&perm[i0];
            int2 pd0 = make_int2(pA.x, pA.y);
            int2 pd1 = rem > 1 ? make_int2(pA.z, pA.w) : pd0;
            int2 pd2 = rem > 2 ? make_int2(pB.x, pB.y) : pd0;
            int2 pd3 = rem > 3 ? make_int2(pB.z, pB.w) : pd0;
            uint4 a0 = *(const uint4*)&Ab[(size_t)pd0.x * 256 + col];
            uint4 b0 = *(const uint4*)&Bb[(size_t)pd0.y * 256 + col];
            uint4 a1 = *(const uint4*)&Ab[(size_t)pd1.x * 256 + col];
            uint4 b1 = *(const uint4*)&Bb[(size_t)pd1.y * 256 + col];
            uint4 a2 = *(const uint4*)&Ab[(size_t)pd2.x * 256 + col];
            uint4 b2v = *(const uint4*)&Bb[(size_t)pd2.y * 256 + col];
            uint4 a3 = *(const uint4*)&Ab[(size_t)pd3.x * 256 + col];
            uint4 b3 = *(const uint4*)&Bb[(size_t)pd3.y * 256 + col];
            float r0 = dot8relu_f16(a0, b0, w2p);
            float r1 = dot8relu_f16(a1, b1, w2p);
            float r2 = dot8relu_f16(a2, b2v, w2p);
            float r3 = dot8relu_f16(a3, b3, w2p);
#pragma unroll
            for (int off = 16; off; off >>= 1) {
                r0 += __shfl_down(r0, off, 32);
                r1 += __shfl_down(r1, off, 32);
                r2 += __shfl_down(r2, off, 32);
                r3 += __shfl_down(r3, off, 32);
            }
            if (l32 == 0) {
                out[pm.x] = r0 + b2;
                if (rem > 1) out[pm.y] = r1 + b2;
                if (rem > 2) out[pm.z] = r2 + b2;
                if (rem > 3) out[pm.w] = r3 + b2;
            }
        }
    }
}

extern "C" void kernel_launch(void* const* d_in, const int* in_sizes, int n_in,
                              void* d_out, int out_size, void* d_ws, size_t ws_size,
                              hipStream_t stream) {
    const float* x   = (const float*)d_in[0];
    const int*   ei  = (const int*)d_in[1];
    const float* ew  = (const float*)d_in[2];
    const int*   el  = (const int*)d_in[3];
    const float* Wr1 = (const float*)d_in[4];
    const float* br1 = (const float*)d_in[5];
    const float* Wo1 = (const float*)d_in[6];
    const float* Wr2 = (const float*)d_in[7];
    const float* br2 = (const float*)d_in[8];
    const float* Wo2 = (const float*)d_in[9];
    const float* Wr3 = (const float*)d_in[10];
    const float* br3 = (const float*)d_in[11];
    const float* Wo3 = (const float*)d_in[12];
    const float* Wd1 = (const float*)d_in[13];
    const float* bd1 = (const float*)d_in[14];
    const float* Wd2 = (const float*)d_in[15];
    const float* bd2 = (const float*)d_in[16];
    float* out = (float*)d_out;

    char* ws = (char*)d_ws;
    size_t o = 0;
    auto alloc = [&](size_t bytes) { size_t p = o; o += (bytes + 255) & ~(size_t)255; return (void*)(ws + p); };
    // cnt + gcur adjacent -> single memset
    int*     cnt     = (int*)alloc(N_NODES * 4);
    int*     gcur    = (int*)alloc(NBUCK2 * 16 * 4);
    size_t   zero_bytes = (size_t)((char*)gcur - (char*)cnt) + NBUCK2 * 16 * 4;
    int*     cursor  = (int*)alloc(N_NODES * 4);
    int*     off     = (int*)alloc((N_NODES + 1) * 4);
    int*     csr_src = (int*)alloc(N_EDGES * 4);
    float*   csr_ew  = (float*)alloc(N_EDGES * 4);
    int2*    psd     = (int2*)alloc((size_t)NBUCK2 * BCAP * 8);
    int*     pperm   = (int*)alloc((size_t)NBUCK2 * BCAP * 4);
    // activation buffers (hi always; lo only used for z)
    ushort_t* ash = (ushort_t*)alloc((size_t)N_NODES * 256 * 2);
    ushort_t* asl = (ushort_t*)alloc((size_t)N_NODES * 256 * 2);
    // GEMM outputs: P bf16 (later Atab f16), R fp32 (later Btab f16)
    ushort_t* Pb  = (ushort_t*)alloc((size_t)N_NODES * 256 * 2);
    float*    Rb  = (float*)alloc((size_t)N_NODES * 256 * 4);
    // pre-split transposed weights (hi only)
    ushort_t* r1h = (ushort_t*)alloc(256 * 256 * 2);
    ushort_t* o1h = (ushort_t*)alloc(256 * 256 * 2);
    ushort_t* r2h = (ushort_t*)alloc(128 * 256 * 2);
    ushort_t* o2h = (ushort_t*)alloc(128 * 256 * 2);
    ushort_t* r3h = (ushort_t*)alloc(128 * 128 * 2);
    ushort_t* o3h = (ushort_t*)alloc(128 * 128 * 2);
    ushort_t* dah = (ushort_t*)alloc(256 * 128 * 2);
    ushort_t* dbh = (ushort_t*)alloc(256 * 128 * 2);
    _Float16* Atab = (_Float16*)Pb;
    _Float16* Btab = (_Float16*)Rb;

    hipMemsetAsync(cnt, 0, zero_bytes, stream);

    // pre-split weights + x
    {
        dim3 g(8, 8, 8);
        k_wsplit<<<g, 256, 0, stream>>>(Wr1, Wo1, Wr2, Wo2, Wr3, Wo3, Wd1,
                                        r1h, o1h, r2h, o2h, r3h, o3h, dah, dbh);
    }
    k_xsplit<<<(N_NODES * 256 / 4 + 255) / 256, 256, 0, stream>>>(x, ash, N_NODES * 256 / 4);

    // CSR build (edges by dst)
    k_hist<<<(N_EDGES + 255) / 256, 256, 0, stream>>>(ei, cnt);
    k_scan<<<1, 1024, 0, stream>>>(cnt, off, cursor);
    k_scatter<<<(N_EDGES + 255) / 256, 256, 0, stream>>>(ei, ew, cursor, csr_src, csr_ew);

    // pair bucket sort
    k_pscatter<<<512, 256, 0, stream>>>(el, gcur, psd, pperm);

    const int AGG_BLOCKS = (N_NODES + 3) / 4;
    const int GX = (N_NODES + 63) / 64;

    // Layer 1 (plain bf16 A)
    k_gemm_bf<false, ushort_t, float><<<dim3(GX, 4), 256, 0, stream>>>(ash, asl, r1h, o1h, nullptr,
                                                                       Pb, Rb, N_NODES, 256, 256);
    k_aggf<256, true, false><<<AGG_BLOCKS, 256, 0, stream>>>(Pb, Rb, br1, off, csr_src, csr_ew, ash, asl);

    // Layer 2 (plain bf16 A)
    k_gemm_bf<false, ushort_t, float><<<dim3(GX, 2), 256, 0, stream>>>(ash, asl, r2h, o2h, nullptr,
                                                                       Pb, Rb, N_NODES, 256, 128);
    k_aggf<128, true, false><<<AGG_BLOCKS, 256, 0, stream>>>(Pb, Rb, br2, off, csr_src, csr_ew, ash, asl);

    // Layer 3 (plain bf16 A; emit z as hi/lo for decoder-table GEMM)
    k_gemm_bf<false, ushort_t, float><<<dim3(GX, 2), 256, 0, stream>>>(ash, asl, r3h, o3h, nullptr,
                                                                       Pb, Rb, N_NODES, 128, 128);
    k_aggf<128, false, true><<<AGG_BLOCKS, 256, 0, stream>>>(Pb, Rb, br3, off, csr_src, csr_ew, ash, asl);

    // Decoder tables (f16): Atab = z@Wd1_top + bd1, Btab = z@Wd1_bot  (A = z hi/lo)
    k_gemm_bf<true, _Float16, _Float16><<<dim3(GX, 4), 256, 0, stream>>>(ash, asl, dah, dbh, bd1,
                                                                         Atab, Btab, N_NODES, 128, 256);

    // Decoder (bucket-sorted, XCD-affine, half-wave/pair, 4 pairs/iter)
    k_decoder<<<2048, 256, 0, stream>>>(Atab, Btab, psd, pperm, gcur, Wd2, bd2, out);
}